// Round 3
// baseline (945.166 us; speedup 1.0000x reference)
//
#include <hip/hip_runtime.h>
#include <stdint.h>

#define S_LEN 2048
#define EMB   4096
#define NHEAD 32
#define DHEAD 128
#define NBLK  32
#define GDIM  64

typedef float  f32x4  __attribute__((ext_vector_type(4)));
typedef __bf16 bf16x8 __attribute__((ext_vector_type(8)));
typedef unsigned short u16;

__device__ __forceinline__ u16 f2bf(float f) {
  uint32_t u = __float_as_uint(f);
  u += 0x7fffu + ((u >> 16) & 1u);
  return (u16)(u >> 16);
}
__device__ __forceinline__ float bf2f(u16 u) {
  return __uint_as_float(((uint32_t)u) << 16);
}

__device__ __forceinline__ void ld_lds16(const u16* g, u16* l) {
  __builtin_amdgcn_global_load_lds((const __attribute__((address_space(1))) void*)g,
                                   (__attribute__((address_space(3))) void*)l, 16, 0, 0);
}

// fp32 -> bf16 bulk convert (vectorized, n4 = n/4)
__global__ void conv_f32_bf16(const float* __restrict__ in, u16* __restrict__ out, int n4) {
  int i = blockIdx.x * 256 + threadIdx.x;
  if (i >= n4) return;
  float4 v = ((const float4*)in)[i];
  ushort4 o;
  o.x = f2bf(v.x); o.y = f2bf(v.y); o.z = f2bf(v.z); o.w = f2bf(v.w);
  ((ushort4*)out)[i] = o;
}

// three weights in one dispatch (grid.y selects)
__global__ void conv3_f32_bf16(const float* __restrict__ a, const float* __restrict__ b,
                               const float* __restrict__ c, u16* __restrict__ oa,
                               u16* __restrict__ ob, u16* __restrict__ oc, int n4) {
  int i = blockIdx.x * 256 + threadIdx.x;
  if (i >= n4) return;
  const float* in = (blockIdx.y == 0) ? a : (blockIdx.y == 1) ? b : c;
  u16* out = (blockIdx.y == 0) ? oa : (blockIdx.y == 1) ? ob : oc;
  float4 v = ((const float4*)in)[i];
  ushort4 o;
  o.x = f2bf(v.x); o.y = f2bf(v.y); o.z = f2bf(v.z); o.w = f2bf(v.w);
  ((ushort4*)out)[i] = o;
}

// ---------------------------------------------------------------------------
// Fused QKV projection, 256x256 tile / BK=64 / 8-phase counted-vmcnt schedule.
// grid (48, 8): blockIdx.x = (which,nt), blockIdx.y = m-tile. Natural dispatch
// order (48%8==0) gives each XCD a fixed set of 6 B-panels across all m-tiles
// (B-panel L2-resident) and co-temporal A across XCDs via L3 — measured better
// than explicit XCD remap (r2: FETCH 177->410 MB with remap; reverted).
// 512 thr = 8 waves (2M x 4N), per-wave 128x64 out.
// LDS 128 KiB: A[2 dbuf][2 half][128x64 bf16], B likewise.
// Per K-tile, 4 phases (C-quadrants); counted vmcnt(4), never 0 in steady state.
// Swizzle: slot s' = s ^ (row&7), applied on pre-swizzled GLOBAL source
// (linear global_load_lds dest) and on the ds_read address (both-sides rule).
// ---------------------------------------------------------------------------
__global__ void __launch_bounds__(512, 2) qkv_gemm_256(
    const u16* __restrict__ A, const u16* __restrict__ Bq, const u16* __restrict__ Bk,
    const u16* __restrict__ Bv, u16* __restrict__ outq, u16* __restrict__ outk,
    u16* __restrict__ outvt, const float* __restrict__ cosp, const float* __restrict__ sinp)
{
  extern __shared__ u16 lds[];   // 65536 u16 = 128 KiB; A: [0,32768) B: [32768,65536)

  const int tid  = threadIdx.x;
  const int w    = tid >> 6;
  const int lane = tid & 63;
  const int r    = lane & 15;
  const int qd   = lane >> 4;
  const int wr   = w >> 2;            // M half-of-wave-grid 0..1
  const int wc   = w & 3;             // N strip 0..3
  const int hh   = wc >> 1;           // head within the 2-head n-tile

  const int which = blockIdx.x >> 4;  // 0=Q 1=K 2=V
  const int nt    = blockIdx.x & 15;
  const int m0    = blockIdx.y * 256;
  const int n0    = nt * 256;
  const int K     = EMB;
  const u16* Bm = (which == 0) ? Bq : (which == 1) ? Bk : Bv;

  // ds_read constants: frag addr = rowbase + frag_step + swz[k]
  const int swz0 = (qd ^ (r & 7)) * 8;
  const int swz1 = ((4 + qd) ^ (r & 7)) * 8;
  const int rowbaseA = (wr * 64 + r) * 64;
  const int rowbaseB = (hh * 64 + (wc & 1) * 16 + r) * 64;

  // staging constants: thread stages LDS row (j*64 + tid>>3), slot tid&7,
  // holding logical k-chunk s = (tid&7)^((tid>>3)&7) (pre-swizzled source).
  const int srw = tid >> 3;
  const int sgs = ((tid & 7) ^ (srw & 7)) * 8;
  const u16* pA0 = A + (size_t)(m0 + srw) * K + sgs;
  const int fm = ((srw >> 5) & 1) * 64 + (srw & 31);     // B col permutation (h0)
  const u16* pB0 = Bm + (size_t)(n0 + fm) * K + sgs;

  f32x4 acc[8][4];
#pragma unroll
  for (int mi = 0; mi < 8; ++mi)
#pragma unroll
    for (int ni = 0; ni < 4; ++ni) acc[mi][ni] = (f32x4){0.f, 0.f, 0.f, 0.f};

  auto stA = [&](int tt, int half) {
    u16* d = lds + ((tt & 1) * 2 + half) * 8192 + w * 512;
    const u16* g = pA0 + (size_t)(half * 128) * K + tt * 64;
    ld_lds16(g, d);
    ld_lds16(g + (size_t)64 * K, d + 4096);
  };
  auto stB = [&](int tt, int half) {
    u16* d = lds + 32768 + ((tt & 1) * 2 + half) * 8192 + w * 512;
    const u16* g = pB0 + (size_t)(half * 32) * K + tt * 64;
    ld_lds16(g, d);
    ld_lds16(g + (size_t)128 * K, d + 4096);
  };

  // prologue: tile 0 fully staged into buf0, drained once.
  stA(0, 0); stB(0, 0); stB(0, 1); stA(0, 1);
  asm volatile("s_waitcnt vmcnt(0)" ::: "memory");
  __builtin_amdgcn_s_barrier();

  for (int t = 0; t < 64; ++t) {
    const u16* bufA = lds + (t & 1) * 16384;
    const u16* bufB = lds + 32768 + (t & 1) * 16384;
    bf16x8 aF[4][2], bLo[2][2], bHi[2][2];

    // ---------------- P1: quadrant (m0-3 x n0-1): needs A h0 + B h0
    {
      const u16* ab = bufA + rowbaseA;
      const u16* bb = bufB + rowbaseB;
#pragma unroll
      for (int mi = 0; mi < 4; ++mi) {
        aF[mi][0] = *(const bf16x8*)(ab + mi * 1024 + swz0);
        aF[mi][1] = *(const bf16x8*)(ab + mi * 1024 + swz1);
      }
#pragma unroll
      for (int ni = 0; ni < 2; ++ni) {
        bLo[ni][0] = *(const bf16x8*)(bb + ni * 2048 + swz0);
        bLo[ni][1] = *(const bf16x8*)(bb + ni * 2048 + swz1);
      }
    }
    if (t < 63) stA(t + 1, 0);
    __builtin_amdgcn_s_barrier();
    asm volatile("s_waitcnt lgkmcnt(0)" ::: "memory");
    __builtin_amdgcn_sched_barrier(0);
    __builtin_amdgcn_s_setprio(1);
#pragma unroll
    for (int mi = 0; mi < 4; ++mi)
#pragma unroll
      for (int ni = 0; ni < 2; ++ni) {
        acc[mi][ni] = __builtin_amdgcn_mfma_f32_16x16x32_bf16(aF[mi][0], bLo[ni][0], acc[mi][ni], 0, 0, 0);
        acc[mi][ni] = __builtin_amdgcn_mfma_f32_16x16x32_bf16(aF[mi][1], bLo[ni][1], acc[mi][ni], 0, 0, 0);
      }
    __builtin_amdgcn_s_setprio(0);
    if (t < 63) asm volatile("s_waitcnt vmcnt(4)" ::: "memory");   // retires B_t h1
    else        asm volatile("s_waitcnt vmcnt(2)" ::: "memory");
    __builtin_amdgcn_s_barrier();

    // ---------------- P2: quadrant (m0-3 x n2-3): needs B h1
    {
      const u16* bb = bufB + 8192 + rowbaseB;
#pragma unroll
      for (int ni = 0; ni < 2; ++ni) {
        bHi[ni][0] = *(const bf16x8*)(bb + ni * 2048 + swz0);
        bHi[ni][1] = *(const bf16x8*)(bb + ni * 2048 + swz1);
      }
    }
    if (t < 63) stB(t + 1, 0);
    __builtin_amdgcn_s_barrier();
    asm volatile("s_waitcnt lgkmcnt(0)" ::: "memory");
    __builtin_amdgcn_sched_barrier(0);
    __builtin_amdgcn_s_setprio(1);
#pragma unroll
    for (int mi = 0; mi < 4; ++mi)
#pragma unroll
      for (int ni = 0; ni < 2; ++ni) {
        acc[mi][ni + 2] = __builtin_amdgcn_mfma_f32_16x16x32_bf16(aF[mi][0], bHi[ni][0], acc[mi][ni + 2], 0, 0, 0);
        acc[mi][ni + 2] = __builtin_amdgcn_mfma_f32_16x16x32_bf16(aF[mi][1], bHi[ni][1], acc[mi][ni + 2], 0, 0, 0);
      }
    __builtin_amdgcn_s_setprio(0);
    if (t < 63) asm volatile("s_waitcnt vmcnt(4)" ::: "memory");   // retires A_t h1
    else        asm volatile("s_waitcnt vmcnt(0)" ::: "memory");
    __builtin_amdgcn_s_barrier();

    // ---------------- P3: quadrant (m4-7 x n2-3): needs A h1
    {
      const u16* ab = bufA + 8192 + rowbaseA;
#pragma unroll
      for (int mi = 0; mi < 4; ++mi) {
        aF[mi][0] = *(const bf16x8*)(ab + mi * 1024 + swz0);
        aF[mi][1] = *(const bf16x8*)(ab + mi * 1024 + swz1);
      }
    }
    if (t < 63) stB(t + 1, 1);
    __builtin_amdgcn_s_barrier();
    asm volatile("s_waitcnt lgkmcnt(0)" ::: "memory");
    __builtin_amdgcn_sched_barrier(0);
    __builtin_amdgcn_s_setprio(1);
#pragma unroll
    for (int mi = 0; mi < 4; ++mi)
#pragma unroll
      for (int ni = 0; ni < 2; ++ni) {
        acc[mi + 4][ni + 2] = __builtin_amdgcn_mfma_f32_16x16x32_bf16(aF[mi][0], bHi[ni][0], acc[mi + 4][ni + 2], 0, 0, 0);
        acc[mi + 4][ni + 2] = __builtin_amdgcn_mfma_f32_16x16x32_bf16(aF[mi][1], bHi[ni][1], acc[mi + 4][ni + 2], 0, 0, 0);
      }
    __builtin_amdgcn_s_setprio(0);
    __builtin_amdgcn_s_barrier();

    // ---------------- P4: quadrant (m4-7 x n0-1): register-only
    if (t < 63) stA(t + 1, 1);
    __builtin_amdgcn_s_barrier();
    __builtin_amdgcn_s_setprio(1);
#pragma unroll
    for (int mi = 0; mi < 4; ++mi)
#pragma unroll
      for (int ni = 0; ni < 2; ++ni) {
        acc[mi + 4][ni] = __builtin_amdgcn_mfma_f32_16x16x32_bf16(aF[mi][0], bLo[ni][0], acc[mi + 4][ni], 0, 0, 0);
        acc[mi + 4][ni] = __builtin_amdgcn_mfma_f32_16x16x32_bf16(aF[mi][1], bLo[ni][1], acc[mi + 4][ni], 0, 0, 0);
      }
    __builtin_amdgcn_s_setprio(0);
    if (t < 63) asm volatile("s_waitcnt vmcnt(4)" ::: "memory");   // retires A,B_{t+1} h0
    __builtin_amdgcn_s_barrier();
  }

  // C-frag mapping: row = m0 + (mi>>2)*128 + wr*64 + (mi&3)*16 + qd*4 + rg
  //                 col = n0 + hh*128 + (ni>>1)*32 + (wc&1)*16 + (ni&1)*64 + r
  if (which < 2) {
    u16* out = which ? outk : outq;
    const int hh_out = 2 * nt + hh;
#pragma unroll
    for (int mi = 0; mi < 8; ++mi) {
      const int rbase = m0 + (mi >> 2) * 128 + wr * 64 + (mi & 3) * 16 + qd * 4;
#pragma unroll
      for (int pp = 0; pp < 2; ++pp) {           // RoPE pairs (ni 2pp, 2pp+1)
        const int dlo = pp * 32 + (wc & 1) * 16 + r;
#pragma unroll
        for (int rg = 0; rg < 4; ++rg) {
          int srow = rbase + rg;
          float c = cosp[srow * DHEAD + dlo];
          float s = sinp[srow * DHEAD + dlo];
          float lo = acc[mi][pp * 2 + 0][rg], hi = acc[mi][pp * 2 + 1][rg];
          size_t base = ((size_t)hh_out * S_LEN + srow) * DHEAD;
          out[base + dlo]      = f2bf(lo * c - hi * s);
          out[base + dlo + 64] = f2bf(hi * c + lo * s);
        }
      }
    }
  } else {
    // V: transpose 256x256 tile through LDS in two 128-row chunks -> (H, D, S)
    u16* lT = lds;  // [256 cols][136]
#pragma unroll
    for (int ch = 0; ch < 2; ++ch) {
      __syncthreads();
#pragma unroll
      for (int mq = 0; mq < 4; ++mq) {
        const int mi = ch * 4 + mq;
        const int lr = wr * 64 + mq * 16 + qd * 4;
#pragma unroll
        for (int ni = 0; ni < 4; ++ni) {
          const int col = hh * 128 + (ni >> 1) * 32 + (wc & 1) * 16 + (ni & 1) * 64 + r;
#pragma unroll
          for (int rg = 0; rg < 4; ++rg)
            lT[col * 136 + lr + rg] = f2bf(acc[mi][ni][rg]);
        }
      }
      __syncthreads();
      const int c = tid >> 1, sh = (tid & 1) * 64;
      const int hh2 = 2 * nt + (c >> 7), d = c & 127;
      size_t obase = ((size_t)hh2 * DHEAD + d) * S_LEN + m0 + ch * 128 + sh;
#pragma unroll
      for (int i8 = 0; i8 < 8; ++i8) {
        uint4 v = *(const uint4*)&lT[c * 136 + sh + i8 * 8];
        *(uint4*)&outvt[obase + i8 * 8] = v;
      }
    }
  }
}

// Output projection: C(2048x4096) = ctx @ Wo^T, f32 out. Natural dispatch order
// (32%8==0: each XCD keeps a fixed 4-panel B working set; r2 remap regressed).
__global__ void __launch_bounds__(256, 2) gemm_out(
    const u16* __restrict__ A, const u16* __restrict__ B, float* __restrict__ out)
{
  __shared__ u16 lA[128 * 32];
  __shared__ u16 lB[128 * 32];
  const int tid = threadIdx.x;
  const int w = tid >> 6, lane = tid & 63;
  const int r = lane & 15, qd = lane >> 4;
  const int m0 = blockIdx.y * 128, n0 = blockIdx.x * 128;
  const int K = EMB;

  f32x4 acc[2][8];
#pragma unroll
  for (int mi = 0; mi < 2; ++mi)
#pragma unroll
    for (int ni = 0; ni < 8; ++ni) acc[mi][ni] = (f32x4){0.f, 0.f, 0.f, 0.f};

  const u16* Ab = A + (size_t)(m0 + w * 16 + (lane >> 2)) * K + (lane & 3) * 8;
  const u16* Bb = B + (size_t)(n0 + w * 16 + (lane >> 2)) * K + (lane & 3) * 8;
  u16* lAb = &lA[(w * 16) * 32];
  u16* lBb = &lB[(w * 16) * 32];

  for (int k0 = 0; k0 < K; k0 += 32) {
    __syncthreads();
    ld_lds16(Ab + k0, lAb);
    ld_lds16(Ab + (size_t)64 * K + k0, lAb + 64 * 32);
    ld_lds16(Bb + k0, lBb);
    ld_lds16(Bb + (size_t)64 * K + k0, lBb + 64 * 32);
    __syncthreads();
    bf16x8 af0 = *(const bf16x8*)&lA[(w * 32 + r) * 32 + qd * 8];
    bf16x8 af1 = *(const bf16x8*)&lA[(w * 32 + 16 + r) * 32 + qd * 8];
#pragma unroll
    for (int ni = 0; ni < 8; ++ni) {
      bf16x8 bf = *(const bf16x8*)&lB[(ni * 16 + r) * 32 + qd * 8];
      acc[0][ni] = __builtin_amdgcn_mfma_f32_16x16x32_bf16(af0, bf, acc[0][ni], 0, 0, 0);
      acc[1][ni] = __builtin_amdgcn_mfma_f32_16x16x32_bf16(af1, bf, acc[1][ni], 0, 0, 0);
    }
  }
#pragma unroll
  for (int mi = 0; mi < 2; ++mi)
#pragma unroll
    for (int ni = 0; ni < 8; ++ni)
#pragma unroll
      for (int rg = 0; rg < 4; ++rg) {
        int srow = m0 + w * 32 + mi * 16 + qd * 4 + rg;
        out[(size_t)srow * EMB + n0 + ni * 16 + r] = acc[mi][ni][rg];
      }
}

// ---------------------------------------------------------------------------
// flash attention, barrier-free K-loop: K and V^T fragments are read DIRECTLY
// from global (L2-resident: 1 MB/head) as 16B bf16x8 loads -- no lK/lV staging,
// no __syncthreads in the K-loop (lP is wave-private). LDS 10 KB; 3 blocks/CU.
// Load-balanced: block x processes q-blocks x and 31-x (33 K-tiles).
// ---------------------------------------------------------------------------
__global__ void __launch_bounds__(256, 3) attn_fwd(
    const u16* __restrict__ qg, const u16* __restrict__ kg, const u16* __restrict__ vtg,
    u16* __restrict__ ctx, float* __restrict__ bmax)
{
  __shared__ u16 lP[64 * 76];
  __shared__ float lBM[4 * NBLK];

  const int tid = threadIdx.x;
  const int w = tid >> 6, lane = tid & 63;
  const int r = lane & 15, qd = lane >> 4;
  const int h = blockIdx.y;
  const u16* ksrc = kg + (size_t)h * S_LEN * DHEAD;
  const u16* vsrc = vtg + (size_t)h * DHEAD * S_LEN;
  const float scale = 0.08838834764831845f;

  for (int qsel = 0; qsel < 2; ++qsel) {
    const int qb = qsel ? (31 - (int)blockIdx.x) : (int)blockIdx.x;

    bf16x8 qf[4];
    {
      const u16* qp = qg + ((size_t)h * S_LEN + qb * 64 + w * 16 + r) * DHEAD + qd * 8;
#pragma unroll
      for (int ki = 0; ki < 4; ++ki) qf[ki] = *(const bf16x8*)(qp + ki * 32);
    }

    f32x4 o[8];
#pragma unroll
    for (int dt = 0; dt < 8; ++dt) o[dt] = (f32x4){0.f, 0.f, 0.f, 0.f};
    float m_run[4], l_run[4];
#pragma unroll
    for (int rg = 0; rg < 4; ++rg) { m_run[rg] = -__builtin_inff(); l_run[rg] = 0.f; }

    for (int kb = 0; kb <= qb; ++kb) {
      const u16* kbase = ksrc + (size_t)(kb * 64) * DHEAD;
      const u16* vbase = vsrc + kb * 64;

      f32x4 sf[4];
#pragma unroll
      for (int nt = 0; nt < 4; ++nt) sf[nt] = (f32x4){0.f, 0.f, 0.f, 0.f};
#pragma unroll
      for (int ki = 0; ki < 4; ++ki)
#pragma unroll
        for (int nt = 0; nt < 4; ++nt) {
          bf16x8 bf = *(const bf16x8*)(kbase + (size_t)(nt * 16 + r) * DHEAD + ki * 32 + qd * 8);
          sf[nt] = __builtin_amdgcn_mfma_f32_16x16x32_bf16(qf[ki], bf, sf[nt], 0, 0, 0);
        }

      float rmax[4];
#pragma unroll
      for (int rg = 0; rg < 4; ++rg) rmax[rg] = -__builtin_inff();
#pragma unroll
      for (int nt = 0; nt < 4; ++nt)
#pragma unroll
        for (int rg = 0; rg < 4; ++rg) {
          float s = sf[nt][rg] * scale;
          if (kb == qb) {
            int col = nt * 16 + r, row = w * 16 + qd * 4 + rg;
            if (col > row) s = -__builtin_inff();
          }
          sf[nt][rg] = s;
          rmax[rg] = fmaxf(rmax[rg], s);
        }
#pragma unroll
      for (int rg = 0; rg < 4; ++rg) {
        float v = rmax[rg];
        v = fmaxf(v, __shfl_xor(v, 1));
        v = fmaxf(v, __shfl_xor(v, 2));
        v = fmaxf(v, __shfl_xor(v, 4));
        v = fmaxf(v, __shfl_xor(v, 8));
        rmax[rg] = v;
      }
      {  // per-wave tile max -> lBM for gate_target block_max
        float v = fmaxf(fmaxf(rmax[0], rmax[1]), fmaxf(rmax[2], rmax[3]));
        v = fmaxf(v, __shfl_xor(v, 16));
        v = fmaxf(v, __shfl_xor(v, 32));
        if (lane == 0) lBM[w * NBLK + kb] = v;
      }

      float alpha[4], rsum[4];
#pragma unroll
      for (int rg = 0; rg < 4; ++rg) {
        float mn = fmaxf(m_run[rg], rmax[rg]);
        alpha[rg] = __expf(m_run[rg] - mn);
        m_run[rg] = mn;
        rsum[rg] = 0.f;
      }
#pragma unroll
      for (int nt = 0; nt < 4; ++nt)
#pragma unroll
        for (int rg = 0; rg < 4; ++rg) {
          float p = __expf(sf[nt][rg] - m_run[rg]);
          sf[nt][rg] = p;
          rsum[rg] += p;
        }
#pragma unroll
      for (int rg = 0; rg < 4; ++rg) {
        float v = rsum[rg];
        v += __shfl_xor(v, 1);
        v += __shfl_xor(v, 2);
        v += __shfl_xor(v, 4);
        v += __shfl_xor(v, 8);
        l_run[rg] = l_run[rg] * alpha[rg] + v;
      }
      // P (C-layout) -> LDS -> A-layout; wave-private rows, no barrier needed
#pragma unroll
      for (int nt = 0; nt < 4; ++nt)
#pragma unroll
        for (int rg = 0; rg < 4; ++rg)
          lP[(w * 16 + qd * 4 + rg) * 76 + nt * 16 + r] = f2bf(sf[nt][rg]);
#pragma unroll
      for (int dt = 0; dt < 8; ++dt)
#pragma unroll
        for (int rg = 0; rg < 4; ++rg) o[dt][rg] *= alpha[rg];
      bf16x8 pa0 = *(const bf16x8*)&lP[(w * 16 + r) * 76 + qd * 8];
      bf16x8 pa1 = *(const bf16x8*)&lP[(w * 16 + r) * 76 + 32 + qd * 8];
#pragma unroll
      for (int dt = 0; dt < 8; ++dt) {
        bf16x8 bv0 = *(const bf16x8*)(vbase + (size_t)(dt * 16 + r) * S_LEN + qd * 8);
        bf16x8 bv1 = *(const bf16x8*)(vbase + (size_t)(dt * 16 + r) * S_LEN + 32 + qd * 8);
        o[dt] = __builtin_amdgcn_mfma_f32_16x16x32_bf16(pa0, bv0, o[dt], 0, 0, 0);
        o[dt] = __builtin_amdgcn_mfma_f32_16x16x32_bf16(pa1, bv1, o[dt], 0, 0, 0);
      }
    }

    float inv[4];
#pragma unroll
    for (int rg = 0; rg < 4; ++rg) inv[rg] = 1.f / l_run[rg];
#pragma unroll
    for (int dt = 0; dt < 8; ++dt)
#pragma unroll
      for (int rg = 0; rg < 4; ++rg) {
        int srow = qb * 64 + w * 16 + qd * 4 + rg;
        ctx[(size_t)srow * EMB + h * DHEAD + dt * 16 + r] = f2bf(o[dt][rg] * inv[rg]);
      }
    __syncthreads();
    if (tid <= qb) {
      float v = fmaxf(fmaxf(lBM[0 * NBLK + tid], lBM[1 * NBLK + tid]),
                      fmaxf(lBM[2 * NBLK + tid], lBM[3 * NBLK + tid]));
      bmax[((size_t)h * NBLK + qb) * NBLK + tid] = v;
    }
    __syncthreads();   // lBM reused next qsel; waves are no longer lockstep
  }
}

// per-(h,nb) mean over 64 rows, q and k in one dispatch (grid.z selects). 128 thr, u32 loads.
__global__ void bmean2(const u16* __restrict__ q, const u16* __restrict__ k,
                       float* __restrict__ qo, float* __restrict__ ko) {
  int nb = blockIdx.x, h = blockIdx.y, t = threadIdx.x;
  const u16* x = blockIdx.z ? k : q;
  float* out = blockIdx.z ? ko : qo;
  const u16* p = x + ((size_t)h * S_LEN + nb * 64) * DHEAD + t * 2;
  float s0 = 0.f, s1 = 0.f;
#pragma unroll 8
  for (int i = 0; i < 64; ++i) {
    uint32_t v = *(const uint32_t*)(p + (size_t)i * DHEAD);
    s0 += bf2f((u16)v);
    s1 += bf2f((u16)(v >> 16));
  }
  float2 rr = {s0 * (1.f / 64.f), s1 * (1.f / 64.f)};
  *(float2*)&out[((size_t)h * NBLK + nb) * DHEAD + t * 2] = rr;
}

// gate_pred + gate_target, one block per head
__global__ void __launch_bounds__(256) gate_kernel(
    const float* __restrict__ qm, const float* __restrict__ km,
    const float* __restrict__ Wgq, const float* __restrict__ Wgk,
    const float* __restrict__ bmx, float* __restrict__ gpred, float* __restrict__ gtgt)
{
  __shared__ float gq[NBLK * GDIM], gk[NBLK * GDIM];
  __shared__ float red[256];
  const int h = blockIdx.x, tid = threadIdx.x;

  for (int i = 0; i < 8; ++i) {
    int e = tid + 256 * i;
    int n = e >> 6, g = e & 63;
    const float* qrow = qm + ((size_t)h * NBLK + n) * DHEAD;
    const float* krow = km + ((size_t)h * NBLK + n) * DHEAD;
    const float* wq = Wgq + g * DHEAD;
    const float* wk = Wgk + g * DHEAD;
    float s1 = 0.f, s2 = 0.f;
    for (int d = 0; d < DHEAD; ++d) { s1 += qrow[d] * wq[d]; s2 += krow[d] * wk[d]; }
    gq[e] = s1; gk[e] = s2;
  }
  __syncthreads();

  float gl[4];
  for (int i = 0; i < 4; ++i) {
    int idx = tid + 256 * i;
    int qn = idx >> 5, kn = idx & 31;
    if (kn <= qn) {
      float s = 0.f;
      for (int g = 0; g < GDIM; ++g) s += gq[qn * GDIM + g] * gk[kn * GDIM + g];
      gl[i] = s * 0.125f;
    } else gl[i] = -__builtin_inff();
  }
  float mx = fmaxf(fmaxf(gl[0], gl[1]), fmaxf(gl[2], gl[3]));
  red[tid] = mx; __syncthreads();
  for (int st = 128; st > 0; st >>= 1) { if (tid < st) red[tid] = fmaxf(red[tid], red[tid + st]); __syncthreads(); }
  float gmax = red[0]; __syncthreads();
  float ex[4], lsum = 0.f;
  for (int i = 0; i < 4; ++i) { ex[i] = __expf(gl[i] - gmax); lsum += ex[i]; }
  red[tid] = lsum; __syncthreads();
  for (int st = 128; st > 0; st >>= 1) { if (tid < st) red[tid] += red[tid + st]; __syncthreads(); }
  float invs = 1.f / red[0]; __syncthreads();
  for (int i = 0; i < 4; ++i) gpred[(size_t)h * 1024 + tid + 256 * i] = ex[i] * invs;

  float tl[4];
  for (int i = 0; i < 4; ++i) {
    int idx = tid + 256 * i;
    int qn = idx >> 5, kn = idx & 31;
    tl[i] = (kn <= qn) ? fminf(fmaxf(bmx[(size_t)h * 1024 + idx], -50.f), 50.f) * 0.5f
                       : -__builtin_inff();
  }
  float mx2 = fmaxf(fmaxf(tl[0], tl[1]), fmaxf(tl[2], tl[3]));
  red[tid] = mx2; __syncthreads();
  for (int st = 128; st > 0; st >>= 1) { if (tid < st) red[tid] = fmaxf(red[tid], red[tid + st]); __syncthreads(); }
  float tmax = red[0]; __syncthreads();
  float ex2[4], ls2 = 0.f;
  for (int i = 0; i < 4; ++i) { ex2[i] = __expf(tl[i] - tmax); ls2 += ex2[i]; }
  red[tid] = ls2; __syncthreads();
  for (int st = 128; st > 0; st >>= 1) { if (tid < st) red[tid] += red[tid + st]; __syncthreads(); }
  float inv2 = 1.f / red[0];
  for (int i = 0; i < 4; ++i) gtgt[(size_t)h * 1024 + tid + 256 * i] = ex2[i] * inv2;
}

extern "C" void kernel_launch(void* const* d_in, const int* in_sizes, int n_in,
                              void* d_out, int out_size, void* d_ws, size_t ws_size,
                              hipStream_t stream) {
  const float* hidden = (const float*)d_in[0];
  const float* cosp   = (const float*)d_in[1];
  const float* sinp   = (const float*)d_in[2];
  const float* Wq     = (const float*)d_in[3];
  const float* Wk     = (const float*)d_in[4];
  const float* Wv     = (const float*)d_in[5];
  const float* Wo     = (const float*)d_in[6];
  const float* Wgq    = (const float*)d_in[7];
  const float* Wgk    = (const float*)d_in[8];

  char* ws = (char*)d_ws;
  // ws layout (total exactly 128 MiB):
  u16* wqb = (u16*)ws;                         // 33,554,432 B (Wq bf16; later Wo bf16)
  u16* wkb = (u16*)(ws + 33554432);            // 33,554,432 B (Wk bf16; later bmx/qmn/kmn)
  u16* hid = (u16*)(ws + 67108864);            // 16,777,216 B (hidden bf16; later ctx)
  u16* qbf = (u16*)(ws + 83886080);            // 16,777,216 B
  u16* kbf = (u16*)(ws + 100663296);           // 16,777,216 B
  u16* vtb = (u16*)(ws + 117440512);           // 16,777,216 B  -> end 134,217,728
  // aliases (regions free after qkv_gemm):
  float* bmx = (float*)(ws + 33554432);        // 131,072 B
  float* qmn = (float*)(ws + 33554432 + 131072);
  float* kmn = (float*)(ws + 33554432 + 655360);
  u16* ctx = hid;                              // hid dead after qkv_gemm
  u16* wvb = (u16*)d_out;                      // Wv bf16 staged in d_out scratch (33.5 MB);
                                               // overwritten by gemm_out at the end.

  float* attn_out = (float*)d_out;
  float* gpred = attn_out + (size_t)S_LEN * EMB;
  float* gtgt  = gpred + NHEAD * NBLK * NBLK;

  conv3_f32_bf16<<<dim3(16384, 3), 256, 0, stream>>>(Wq, Wk, Wv, wqb, wkb, wvb, 4194304);
  conv_f32_bf16<<<8192, 256, 0, stream>>>(hidden, hid, 2097152);

  static bool attr_set = false;
  if (!attr_set) {
    (void)hipFuncSetAttribute((const void*)qkv_gemm_256,
                              hipFuncAttributeMaxDynamicSharedMemorySize, 131072);
    attr_set = true;
  }
  qkv_gemm_256<<<dim3(48, 8), 512, 131072, stream>>>(hid, wqb, wkb, wvb, qbf, kbf, vtb, cosp, sinp);

  conv_f32_bf16<<<16384, 256, 0, stream>>>(Wo, wqb, 4194304);  // wqb free after qkv_gemm

  attn_fwd<<<dim3(16, NHEAD), 256, 0, stream>>>(qbf, kbf, vtb, ctx, bmx);

  bmean2<<<dim3(NBLK, NHEAD, 2), 128, 0, stream>>>(qbf, kbf, qmn, kmn);
  gate_kernel<<<NHEAD, 256, 0, stream>>>(qmn, kmn, Wgq, Wgk, bmx, gpred, gtgt);

  gemm_out<<<dim3(32, 16), 256, 0, stream>>>(ctx, wqb, attn_out);
}

// Round 4
// 762.696 us; speedup vs baseline: 1.2392x; 1.2392x over previous
//
#include <hip/hip_runtime.h>
#include <stdint.h>

#define S_LEN 2048
#define EMB   4096
#define NHEAD 32
#define DHEAD 128
#define NBLK  32
#define GDIM  64

typedef float  f32x4  __attribute__((ext_vector_type(4)));
typedef __bf16 bf16x8 __attribute__((ext_vector_type(8)));
typedef unsigned short u16;

__device__ __forceinline__ u16 f2bf(float f) {
  uint32_t u = __float_as_uint(f);
  u += 0x7fffu + ((u >> 16) & 1u);
  return (u16)(u >> 16);
}
__device__ __forceinline__ float bf2f(u16 u) {
  return __uint_as_float(((uint32_t)u) << 16);
}

__device__ __forceinline__ void ld_lds16(const u16* g, u16* l) {
  __builtin_amdgcn_global_load_lds((const __attribute__((address_space(1))) void*)g,
                                   (__attribute__((address_space(3))) void*)l, 16, 0, 0);
}

// fp32 -> bf16 bulk convert (vectorized, n4 = n/4)
__global__ void conv_f32_bf16(const float* __restrict__ in, u16* __restrict__ out, int n4) {
  int i = blockIdx.x * 256 + threadIdx.x;
  if (i >= n4) return;
  float4 v = ((const float4*)in)[i];
  ushort4 o;
  o.x = f2bf(v.x); o.y = f2bf(v.y); o.z = f2bf(v.z); o.w = f2bf(v.w);
  ((ushort4*)out)[i] = o;
}

// three weights in one dispatch (grid.y selects)
__global__ void conv3_f32_bf16(const float* __restrict__ a, const float* __restrict__ b,
                               const float* __restrict__ c, u16* __restrict__ oa,
                               u16* __restrict__ ob, u16* __restrict__ oc, int n4) {
  int i = blockIdx.x * 256 + threadIdx.x;
  if (i >= n4) return;
  const float* in = (blockIdx.y == 0) ? a : (blockIdx.y == 1) ? b : c;
  u16* out = (blockIdx.y == 0) ? oa : (blockIdx.y == 1) ? ob : oc;
  float4 v = ((const float4*)in)[i];
  ushort4 o;
  o.x = f2bf(v.x); o.y = f2bf(v.y); o.z = f2bf(v.z); o.w = f2bf(v.w);
  ((ushort4*)out)[i] = o;
}

// ---------------------------------------------------------------------------
// Fused QKV projection, 256x256 tile / BK=64 / 8-phase counted-vmcnt schedule.
// grid (48, 8). Natural dispatch order (48%8==0) keeps B-panels L2-resident
// per XCD (r2 explicit remap regressed FETCH 177->410 MB; reverted).
// ---------------------------------------------------------------------------
__global__ void __launch_bounds__(512, 2) qkv_gemm_256(
    const u16* __restrict__ A, const u16* __restrict__ Bq, const u16* __restrict__ Bk,
    const u16* __restrict__ Bv, u16* __restrict__ outq, u16* __restrict__ outk,
    u16* __restrict__ outvt, const float* __restrict__ cosp, const float* __restrict__ sinp)
{
  extern __shared__ u16 lds[];   // 65536 u16 = 128 KiB; A: [0,32768) B: [32768,65536)

  const int tid  = threadIdx.x;
  const int w    = tid >> 6;
  const int lane = tid & 63;
  const int r    = lane & 15;
  const int qd   = lane >> 4;
  const int wr   = w >> 2;            // M half-of-wave-grid 0..1
  const int wc   = w & 3;             // N strip 0..3
  const int hh   = wc >> 1;           // head within the 2-head n-tile

  const int which = blockIdx.x >> 4;  // 0=Q 1=K 2=V
  const int nt    = blockIdx.x & 15;
  const int m0    = blockIdx.y * 256;
  const int n0    = nt * 256;
  const int K     = EMB;
  const u16* Bm = (which == 0) ? Bq : (which == 1) ? Bk : Bv;

  // ds_read constants: frag addr = rowbase + frag_step + swz[k]
  const int swz0 = (qd ^ (r & 7)) * 8;
  const int swz1 = ((4 + qd) ^ (r & 7)) * 8;
  const int rowbaseA = (wr * 64 + r) * 64;
  const int rowbaseB = (hh * 64 + (wc & 1) * 16 + r) * 64;

  // staging constants: thread stages LDS row (j*64 + tid>>3), slot tid&7,
  // holding logical k-chunk s = (tid&7)^((tid>>3)&7) (pre-swizzled source).
  const int srw = tid >> 3;
  const int sgs = ((tid & 7) ^ (srw & 7)) * 8;
  const u16* pA0 = A + (size_t)(m0 + srw) * K + sgs;
  const int fm = ((srw >> 5) & 1) * 64 + (srw & 31);     // B col permutation (h0)
  const u16* pB0 = Bm + (size_t)(n0 + fm) * K + sgs;

  f32x4 acc[8][4];
#pragma unroll
  for (int mi = 0; mi < 8; ++mi)
#pragma unroll
    for (int ni = 0; ni < 4; ++ni) acc[mi][ni] = (f32x4){0.f, 0.f, 0.f, 0.f};

  auto stA = [&](int tt, int half) {
    u16* d = lds + ((tt & 1) * 2 + half) * 8192 + w * 512;
    const u16* g = pA0 + (size_t)(half * 128) * K + tt * 64;
    ld_lds16(g, d);
    ld_lds16(g + (size_t)64 * K, d + 4096);
  };
  auto stB = [&](int tt, int half) {
    u16* d = lds + 32768 + ((tt & 1) * 2 + half) * 8192 + w * 512;
    const u16* g = pB0 + (size_t)(half * 32) * K + tt * 64;
    ld_lds16(g, d);
    ld_lds16(g + (size_t)128 * K, d + 4096);
  };

  // prologue: tile 0 fully staged into buf0, drained once.
  stA(0, 0); stB(0, 0); stB(0, 1); stA(0, 1);
  asm volatile("s_waitcnt vmcnt(0)" ::: "memory");
  __builtin_amdgcn_s_barrier();

  for (int t = 0; t < 64; ++t) {
    const u16* bufA = lds + (t & 1) * 16384;
    const u16* bufB = lds + 32768 + (t & 1) * 16384;
    bf16x8 aF[4][2], bLo[2][2], bHi[2][2];

    // ---------------- P1: quadrant (m0-3 x n0-1): needs A h0 + B h0
    {
      const u16* ab = bufA + rowbaseA;
      const u16* bb = bufB + rowbaseB;
#pragma unroll
      for (int mi = 0; mi < 4; ++mi) {
        aF[mi][0] = *(const bf16x8*)(ab + mi * 1024 + swz0);
        aF[mi][1] = *(const bf16x8*)(ab + mi * 1024 + swz1);
      }
#pragma unroll
      for (int ni = 0; ni < 2; ++ni) {
        bLo[ni][0] = *(const bf16x8*)(bb + ni * 2048 + swz0);
        bLo[ni][1] = *(const bf16x8*)(bb + ni * 2048 + swz1);
      }
    }
    if (t < 63) stA(t + 1, 0);
    __builtin_amdgcn_s_barrier();
    asm volatile("s_waitcnt lgkmcnt(0)" ::: "memory");
    __builtin_amdgcn_sched_barrier(0);
    __builtin_amdgcn_s_setprio(1);
#pragma unroll
    for (int mi = 0; mi < 4; ++mi)
#pragma unroll
      for (int ni = 0; ni < 2; ++ni) {
        acc[mi][ni] = __builtin_amdgcn_mfma_f32_16x16x32_bf16(aF[mi][0], bLo[ni][0], acc[mi][ni], 0, 0, 0);
        acc[mi][ni] = __builtin_amdgcn_mfma_f32_16x16x32_bf16(aF[mi][1], bLo[ni][1], acc[mi][ni], 0, 0, 0);
      }
    __builtin_amdgcn_s_setprio(0);
    if (t < 63) asm volatile("s_waitcnt vmcnt(4)" ::: "memory");   // retires B_t h1
    else        asm volatile("s_waitcnt vmcnt(2)" ::: "memory");
    __builtin_amdgcn_s_barrier();

    // ---------------- P2: quadrant (m0-3 x n2-3): needs B h1
    {
      const u16* bb = bufB + 8192 + rowbaseB;
#pragma unroll
      for (int ni = 0; ni < 2; ++ni) {
        bHi[ni][0] = *(const bf16x8*)(bb + ni * 2048 + swz0);
        bHi[ni][1] = *(const bf16x8*)(bb + ni * 2048 + swz1);
      }
    }
    if (t < 63) stB(t + 1, 0);
    __builtin_amdgcn_s_barrier();
    asm volatile("s_waitcnt lgkmcnt(0)" ::: "memory");
    __builtin_amdgcn_sched_barrier(0);
    __builtin_amdgcn_s_setprio(1);
#pragma unroll
    for (int mi = 0; mi < 4; ++mi)
#pragma unroll
      for (int ni = 0; ni < 2; ++ni) {
        acc[mi][ni + 2] = __builtin_amdgcn_mfma_f32_16x16x32_bf16(aF[mi][0], bHi[ni][0], acc[mi][ni + 2], 0, 0, 0);
        acc[mi][ni + 2] = __builtin_amdgcn_mfma_f32_16x16x32_bf16(aF[mi][1], bHi[ni][1], acc[mi][ni + 2], 0, 0, 0);
      }
    __builtin_amdgcn_s_setprio(0);
    if (t < 63) asm volatile("s_waitcnt vmcnt(4)" ::: "memory");   // retires A_t h1
    else        asm volatile("s_waitcnt vmcnt(0)" ::: "memory");
    __builtin_amdgcn_s_barrier();

    // ---------------- P3: quadrant (m4-7 x n2-3): needs A h1
    {
      const u16* ab = bufA + 8192 + rowbaseA;
#pragma unroll
      for (int mi = 0; mi < 4; ++mi) {
        aF[mi][0] = *(const bf16x8*)(ab + mi * 1024 + swz0);
        aF[mi][1] = *(const bf16x8*)(ab + mi * 1024 + swz1);
      }
    }
    if (t < 63) stB(t + 1, 1);
    __builtin_amdgcn_s_barrier();
    asm volatile("s_waitcnt lgkmcnt(0)" ::: "memory");
    __builtin_amdgcn_sched_barrier(0);
    __builtin_amdgcn_s_setprio(1);
#pragma unroll
    for (int mi = 0; mi < 4; ++mi)
#pragma unroll
      for (int ni = 0; ni < 2; ++ni) {
        acc[mi + 4][ni + 2] = __builtin_amdgcn_mfma_f32_16x16x32_bf16(aF[mi][0], bHi[ni][0], acc[mi + 4][ni + 2], 0, 0, 0);
        acc[mi + 4][ni + 2] = __builtin_amdgcn_mfma_f32_16x16x32_bf16(aF[mi][1], bHi[ni][1], acc[mi + 4][ni + 2], 0, 0, 0);
      }
    __builtin_amdgcn_s_setprio(0);
    __builtin_amdgcn_s_barrier();

    // ---------------- P4: quadrant (m4-7 x n0-1): register-only
    if (t < 63) stA(t + 1, 1);
    __builtin_amdgcn_s_barrier();
    __builtin_amdgcn_s_setprio(1);
#pragma unroll
    for (int mi = 0; mi < 4; ++mi)
#pragma unroll
      for (int ni = 0; ni < 2; ++ni) {
        acc[mi + 4][ni] = __builtin_amdgcn_mfma_f32_16x16x32_bf16(aF[mi][0], bLo[ni][0], acc[mi + 4][ni], 0, 0, 0);
        acc[mi + 4][ni] = __builtin_amdgcn_mfma_f32_16x16x32_bf16(aF[mi][1], bLo[ni][1], acc[mi + 4][ni], 0, 0, 0);
      }
    __builtin_amdgcn_s_setprio(0);
    if (t < 63) asm volatile("s_waitcnt vmcnt(4)" ::: "memory");   // retires A,B_{t+1} h0
    __builtin_amdgcn_s_barrier();
  }

  // C-frag mapping: row = m0 + (mi>>2)*128 + wr*64 + (mi&3)*16 + qd*4 + rg
  //                 col = n0 + hh*128 + (ni>>1)*32 + (wc&1)*16 + (ni&1)*64 + r
  if (which < 2) {
    u16* out = which ? outk : outq;
    const int hh_out = 2 * nt + hh;
#pragma unroll
    for (int mi = 0; mi < 8; ++mi) {
      const int rbase = m0 + (mi >> 2) * 128 + wr * 64 + (mi & 3) * 16 + qd * 4;
#pragma unroll
      for (int pp = 0; pp < 2; ++pp) {           // RoPE pairs (ni 2pp, 2pp+1)
        const int dlo = pp * 32 + (wc & 1) * 16 + r;
#pragma unroll
        for (int rg = 0; rg < 4; ++rg) {
          int srow = rbase + rg;
          float c = cosp[srow * DHEAD + dlo];
          float s = sinp[srow * DHEAD + dlo];
          float lo = acc[mi][pp * 2 + 0][rg], hi = acc[mi][pp * 2 + 1][rg];
          size_t base = ((size_t)hh_out * S_LEN + srow) * DHEAD;
          out[base + dlo]      = f2bf(lo * c - hi * s);
          out[base + dlo + 64] = f2bf(hi * c + lo * s);
        }
      }
    }
  } else {
    // V: transpose 256x256 tile through LDS in two 128-row chunks -> (H, D, S)
    u16* lT = lds;  // [256 cols][136]
#pragma unroll
    for (int ch = 0; ch < 2; ++ch) {
      __syncthreads();
#pragma unroll
      for (int mq = 0; mq < 4; ++mq) {
        const int mi = ch * 4 + mq;
        const int lr = wr * 64 + mq * 16 + qd * 4;
#pragma unroll
        for (int ni = 0; ni < 4; ++ni) {
          const int col = hh * 128 + (ni >> 1) * 32 + (wc & 1) * 16 + (ni & 1) * 64 + r;
#pragma unroll
          for (int rg = 0; rg < 4; ++rg)
            lT[col * 136 + lr + rg] = f2bf(acc[mi][ni][rg]);
        }
      }
      __syncthreads();
      const int c = tid >> 1, sh = (tid & 1) * 64;
      const int hh2 = 2 * nt + (c >> 7), d = c & 127;
      size_t obase = ((size_t)hh2 * DHEAD + d) * S_LEN + m0 + ch * 128 + sh;
#pragma unroll
      for (int i8 = 0; i8 < 8; ++i8) {
        uint4 v = *(const uint4*)&lT[c * 136 + sh + i8 * 8];
        *(uint4*)&outvt[obase + i8 * 8] = v;
      }
    }
  }
}

// Output projection: C(2048x4096) = ctx @ Wo^T, f32 out. Natural dispatch order.
__global__ void __launch_bounds__(256, 2) gemm_out(
    const u16* __restrict__ A, const u16* __restrict__ B, float* __restrict__ out)
{
  __shared__ u16 lA[128 * 32];
  __shared__ u16 lB[128 * 32];
  const int tid = threadIdx.x;
  const int w = tid >> 6, lane = tid & 63;
  const int r = lane & 15, qd = lane >> 4;
  const int m0 = blockIdx.y * 128, n0 = blockIdx.x * 128;
  const int K = EMB;

  f32x4 acc[2][8];
#pragma unroll
  for (int mi = 0; mi < 2; ++mi)
#pragma unroll
    for (int ni = 0; ni < 8; ++ni) acc[mi][ni] = (f32x4){0.f, 0.f, 0.f, 0.f};

  const u16* Ab = A + (size_t)(m0 + w * 16 + (lane >> 2)) * K + (lane & 3) * 8;
  const u16* Bb = B + (size_t)(n0 + w * 16 + (lane >> 2)) * K + (lane & 3) * 8;
  u16* lAb = &lA[(w * 16) * 32];
  u16* lBb = &lB[(w * 16) * 32];

  for (int k0 = 0; k0 < K; k0 += 32) {
    __syncthreads();
    ld_lds16(Ab + k0, lAb);
    ld_lds16(Ab + (size_t)64 * K + k0, lAb + 64 * 32);
    ld_lds16(Bb + k0, lBb);
    ld_lds16(Bb + (size_t)64 * K + k0, lBb + 64 * 32);
    __syncthreads();
    bf16x8 af0 = *(const bf16x8*)&lA[(w * 32 + r) * 32 + qd * 8];
    bf16x8 af1 = *(const bf16x8*)&lA[(w * 32 + 16 + r) * 32 + qd * 8];
#pragma unroll
    for (int ni = 0; ni < 8; ++ni) {
      bf16x8 bf = *(const bf16x8*)&lB[(ni * 16 + r) * 32 + qd * 8];
      acc[0][ni] = __builtin_amdgcn_mfma_f32_16x16x32_bf16(af0, bf, acc[0][ni], 0, 0, 0);
      acc[1][ni] = __builtin_amdgcn_mfma_f32_16x16x32_bf16(af1, bf, acc[1][ni], 0, 0, 0);
    }
  }
#pragma unroll
  for (int mi = 0; mi < 2; ++mi)
#pragma unroll
    for (int ni = 0; ni < 8; ++ni)
#pragma unroll
      for (int rg = 0; rg < 4; ++rg) {
        int srow = m0 + w * 32 + mi * 16 + qd * 4 + rg;
        out[(size_t)srow * EMB + n0 + ni * 16 + r] = acc[mi][ni][rg];
      }
}

// ---------------------------------------------------------------------------
// flash attention with double-buffered global_load_lds staging + counted vmcnt.
// Per wave, 8 staging loads per K-tile (4 K + 4 V, 1 KB coalesced each).
// Pipeline: prologue stages tiles 0,1; per tile: vmcnt(8) [tile kb resident,
// kb+1 in flight] -> barrier -> compute -> barrier -> stage kb+2 into the
// just-freed buffer. vmcnt(0) only on the last tile. Prior-qsel ctx stores and
// the qf register loads are older in the vmcnt queue than the waited stage.
// LDS K: [64][128] linear rows, slot-swizzle phys = logical ^ (row&15);
//     V: [128][64] linear rows, phys = logical ^ (row&7); swizzle applied on
// the pre-swizzled GLOBAL source (linear global_load_lds dest) and on ds_read.
// LDS 75 KB -> 2 blocks/CU. Load-balanced: block x does q-blocks x and 31-x.
// ---------------------------------------------------------------------------
__global__ void __launch_bounds__(256, 2) attn_fwd(
    const u16* __restrict__ qg, const u16* __restrict__ kg, const u16* __restrict__ vtg,
    u16* __restrict__ ctx, float* __restrict__ bmax)
{
  __shared__ u16 lK[2][64 * 128];
  __shared__ u16 lV[2][128 * 64];
  __shared__ u16 lP[64 * 76];
  __shared__ float lBM[4 * NBLK];

  const int tid = threadIdx.x;
  const int w = tid >> 6, lane = tid & 63;
  const int r = lane & 15, qd = lane >> 4;
  const int h = blockIdx.y;
  const u16* ksrc = kg + (size_t)h * S_LEN * DHEAD;
  const u16* vsrc = vtg + (size_t)h * DHEAD * S_LEN;
  const float scale = 0.08838834764831845f;

  // staging constants (per thread)
  const int ksl   = (lane & 15) ^ (w * 4 + (lane >> 4));       // K logical slot
  const int krow0 = w * 4 + (lane >> 4);                       // + i*16
  const u16* kg0  = ksrc + (size_t)krow0 * DHEAD + ksl * 8;
  const int vsl   = (lane & 7) ^ (lane >> 3);                  // V logical slot
  const int vrow0 = w * 8 + (lane >> 3);                       // + i*32
  const u16* vg0  = vsrc + (size_t)vrow0 * S_LEN + vsl * 8;

  for (int qsel = 0; qsel < 2; ++qsel) {
    const int qb = qsel ? (31 - (int)blockIdx.x) : (int)blockIdx.x;

    auto stage = [&](int kb, int buf) {
      u16* kd = &lK[buf][w * 512];
      const u16* kgp = kg0 + (size_t)kb * 64 * DHEAD;
#pragma unroll
      for (int i = 0; i < 4; ++i) ld_lds16(kgp + i * 16 * DHEAD, kd + i * 2048);
      u16* vd = &lV[buf][w * 512];
      const u16* vgp = vg0 + kb * 64;
#pragma unroll
      for (int i = 0; i < 4; ++i) ld_lds16(vgp + (size_t)i * 32 * S_LEN, vd + i * 2048);
    };

    stage(0, 0);                       // 8 loads/wave
    bf16x8 qf[4];
    {
      const u16* qp = qg + ((size_t)h * S_LEN + qb * 64 + w * 16 + r) * DHEAD + qd * 8;
#pragma unroll
      for (int ki = 0; ki < 4; ++ki) qf[ki] = *(const bf16x8*)(qp + ki * 32);
    }
    if (qb > 0) stage(1, 1);           // 8 more

    f32x4 o[8];
#pragma unroll
    for (int dt = 0; dt < 8; ++dt) o[dt] = (f32x4){0.f, 0.f, 0.f, 0.f};
    float m_run[4], l_run[4];
#pragma unroll
    for (int rg = 0; rg < 4; ++rg) { m_run[rg] = -__builtin_inff(); l_run[rg] = 0.f; }

    for (int kb = 0; kb <= qb; ++kb) {
      const int buf = kb & 1;
      // tile kb resident; tile kb+1 (8 loads) stays in flight.
      if (kb < qb) asm volatile("s_waitcnt vmcnt(8)" ::: "memory");
      else         asm volatile("s_waitcnt vmcnt(0)" ::: "memory");
      __builtin_amdgcn_s_barrier();

      f32x4 sf[4];
#pragma unroll
      for (int nt = 0; nt < 4; ++nt) sf[nt] = (f32x4){0.f, 0.f, 0.f, 0.f};
      __builtin_amdgcn_s_setprio(1);
#pragma unroll
      for (int ki = 0; ki < 4; ++ki)
#pragma unroll
        for (int nt = 0; nt < 4; ++nt) {
          bf16x8 bf = *(const bf16x8*)&lK[buf][(nt * 16 + r) * 128 + (((ki << 2) + qd) ^ r) * 8];
          sf[nt] = __builtin_amdgcn_mfma_f32_16x16x32_bf16(qf[ki], bf, sf[nt], 0, 0, 0);
        }
      __builtin_amdgcn_s_setprio(0);

      float rmax[4];
#pragma unroll
      for (int rg = 0; rg < 4; ++rg) rmax[rg] = -__builtin_inff();
#pragma unroll
      for (int nt = 0; nt < 4; ++nt)
#pragma unroll
        for (int rg = 0; rg < 4; ++rg) {
          float s = sf[nt][rg] * scale;
          if (kb == qb) {
            int col = nt * 16 + r, row = w * 16 + qd * 4 + rg;
            if (col > row) s = -__builtin_inff();
          }
          sf[nt][rg] = s;
          rmax[rg] = fmaxf(rmax[rg], s);
        }
#pragma unroll
      for (int rg = 0; rg < 4; ++rg) {
        float v = rmax[rg];
        v = fmaxf(v, __shfl_xor(v, 1));
        v = fmaxf(v, __shfl_xor(v, 2));
        v = fmaxf(v, __shfl_xor(v, 4));
        v = fmaxf(v, __shfl_xor(v, 8));
        rmax[rg] = v;
      }
      {  // per-wave tile max -> lBM for gate_target block_max
        float v = fmaxf(fmaxf(rmax[0], rmax[1]), fmaxf(rmax[2], rmax[3]));
        v = fmaxf(v, __shfl_xor(v, 16));
        v = fmaxf(v, __shfl_xor(v, 32));
        if (lane == 0) lBM[w * NBLK + kb] = v;
      }

      float alpha[4], rsum[4];
#pragma unroll
      for (int rg = 0; rg < 4; ++rg) {
        float mn = fmaxf(m_run[rg], rmax[rg]);
        alpha[rg] = __expf(m_run[rg] - mn);
        m_run[rg] = mn;
        rsum[rg] = 0.f;
      }
#pragma unroll
      for (int nt = 0; nt < 4; ++nt)
#pragma unroll
        for (int rg = 0; rg < 4; ++rg) {
          float p = __expf(sf[nt][rg] - m_run[rg]);
          sf[nt][rg] = p;
          rsum[rg] += p;
        }
#pragma unroll
      for (int rg = 0; rg < 4; ++rg) {
        float v = rsum[rg];
        v += __shfl_xor(v, 1);
        v += __shfl_xor(v, 2);
        v += __shfl_xor(v, 4);
        v += __shfl_xor(v, 8);
        l_run[rg] = l_run[rg] * alpha[rg] + v;
      }
      // P (C-layout) -> LDS -> A-layout; wave-private rows
#pragma unroll
      for (int nt = 0; nt < 4; ++nt)
#pragma unroll
        for (int rg = 0; rg < 4; ++rg)
          lP[(w * 16 + qd * 4 + rg) * 76 + nt * 16 + r] = f2bf(sf[nt][rg]);
#pragma unroll
      for (int dt = 0; dt < 8; ++dt)
#pragma unroll
        for (int rg = 0; rg < 4; ++rg) o[dt][rg] *= alpha[rg];
      bf16x8 pa0 = *(const bf16x8*)&lP[(w * 16 + r) * 76 + qd * 8];
      bf16x8 pa1 = *(const bf16x8*)&lP[(w * 16 + r) * 76 + 32 + qd * 8];
      __builtin_amdgcn_s_setprio(1);
#pragma unroll
      for (int dt = 0; dt < 8; ++dt) {
        bf16x8 bv0 = *(const bf16x8*)&lV[buf][(dt * 16 + r) * 64 + (qd ^ (r & 7)) * 8];
        bf16x8 bv1 = *(const bf16x8*)&lV[buf][(dt * 16 + r) * 64 + (((4 + qd)) ^ (r & 7)) * 8];
        o[dt] = __builtin_amdgcn_mfma_f32_16x16x32_bf16(pa0, bv0, o[dt], 0, 0, 0);
        o[dt] = __builtin_amdgcn_mfma_f32_16x16x32_bf16(pa1, bv1, o[dt], 0, 0, 0);
      }
      __builtin_amdgcn_s_setprio(0);

      __builtin_amdgcn_s_barrier();    // all waves done reading buf before restage
      if (kb + 2 <= qb) stage(kb + 2, buf);
    }

    float inv[4];
#pragma unroll
    for (int rg = 0; rg < 4; ++rg) inv[rg] = 1.f / l_run[rg];
#pragma unroll
    for (int dt = 0; dt < 8; ++dt)
#pragma unroll
      for (int rg = 0; rg < 4; ++rg) {
        int srow = qb * 64 + w * 16 + qd * 4 + rg;
        ctx[(size_t)srow * EMB + h * DHEAD + dt * 16 + r] = f2bf(o[dt][rg] * inv[rg]);
      }
    __syncthreads();
    if (tid <= qb) {
      float v = fmaxf(fmaxf(lBM[0 * NBLK + tid], lBM[1 * NBLK + tid]),
                      fmaxf(lBM[2 * NBLK + tid], lBM[3 * NBLK + tid]));
      bmax[((size_t)h * NBLK + qb) * NBLK + tid] = v;
    }
    __syncthreads();   // lBM reused next qsel
  }
}

// per-(h,nb) mean over 64 rows, q and k in one dispatch (grid.z selects). 128 thr, u32 loads.
__global__ void bmean2(const u16* __restrict__ q, const u16* __restrict__ k,
                       float* __restrict__ qo, float* __restrict__ ko) {
  int nb = blockIdx.x, h = blockIdx.y, t = threadIdx.x;
  const u16* x = blockIdx.z ? k : q;
  float* out = blockIdx.z ? ko : qo;
  const u16* p = x + ((size_t)h * S_LEN + nb * 64) * DHEAD + t * 2;
  float s0 = 0.f, s1 = 0.f;
#pragma unroll 8
  for (int i = 0; i < 64; ++i) {
    uint32_t v = *(const uint32_t*)(p + (size_t)i * DHEAD);
    s0 += bf2f((u16)v);
    s1 += bf2f((u16)(v >> 16));
  }
  float2 rr = {s0 * (1.f / 64.f), s1 * (1.f / 64.f)};
  *(float2*)&out[((size_t)h * NBLK + nb) * DHEAD + t * 2] = rr;
}

// gate_pred + gate_target, one block per head
__global__ void __launch_bounds__(256) gate_kernel(
    const float* __restrict__ qm, const float* __restrict__ km,
    const float* __restrict__ Wgq, const float* __restrict__ Wgk,
    const float* __restrict__ bmx, float* __restrict__ gpred, float* __restrict__ gtgt)
{
  __shared__ float gq[NBLK * GDIM], gk[NBLK * GDIM];
  __shared__ float red[256];
  const int h = blockIdx.x, tid = threadIdx.x;

  for (int i = 0; i < 8; ++i) {
    int e = tid + 256 * i;
    int n = e >> 6, g = e & 63;
    const float* qrow = qm + ((size_t)h * NBLK + n) * DHEAD;
    const float* krow = km + ((size_t)h * NBLK + n) * DHEAD;
    const float* wq = Wgq + g * DHEAD;
    const float* wk = Wgk + g * DHEAD;
    float s1 = 0.f, s2 = 0.f;
    for (int d = 0; d < DHEAD; ++d) { s1 += qrow[d] * wq[d]; s2 += krow[d] * wk[d]; }
    gq[e] = s1; gk[e] = s2;
  }
  __syncthreads();

  float gl[4];
  for (int i = 0; i < 4; ++i) {
    int idx = tid + 256 * i;
    int qn = idx >> 5, kn = idx & 31;
    if (kn <= qn) {
      float s = 0.f;
      for (int g = 0; g < GDIM; ++g) s += gq[qn * GDIM + g] * gk[kn * GDIM + g];
      gl[i] = s * 0.125f;
    } else gl[i] = -__builtin_inff();
  }
  float mx = fmaxf(fmaxf(gl[0], gl[1]), fmaxf(gl[2], gl[3]));
  red[tid] = mx; __syncthreads();
  for (int st = 128; st > 0; st >>= 1) { if (tid < st) red[tid] = fmaxf(red[tid], red[tid + st]); __syncthreads(); }
  float gmax = red[0]; __syncthreads();
  float ex[4], lsum = 0.f;
  for (int i = 0; i < 4; ++i) { ex[i] = __expf(gl[i] - gmax); lsum += ex[i]; }
  red[tid] = lsum; __syncthreads();
  for (int st = 128; st > 0; st >>= 1) { if (tid < st) red[tid] += red[tid + st]; __syncthreads(); }
  float invs = 1.f / red[0]; __syncthreads();
  for (int i = 0; i < 4; ++i) gpred[(size_t)h * 1024 + tid + 256 * i] = ex[i] * invs;

  float tl[4];
  for (int i = 0; i < 4; ++i) {
    int idx = tid + 256 * i;
    int qn = idx >> 5, kn = idx & 31;
    tl[i] = (kn <= qn) ? fminf(fmaxf(bmx[(size_t)h * 1024 + idx], -50.f), 50.f) * 0.5f
                       : -__builtin_inff();
  }
  float mx2 = fmaxf(fmaxf(tl[0], tl[1]), fmaxf(tl[2], tl[3]));
  red[tid] = mx2; __syncthreads();
  for (int st = 128; st > 0; st >>= 1) { if (tid < st) red[tid] = fmaxf(red[tid], red[tid + st]); __syncthreads(); }
  float tmax = red[0]; __syncthreads();
  float ex2[4], ls2 = 0.f;
  for (int i = 0; i < 4; ++i) { ex2[i] = __expf(tl[i] - tmax); ls2 += ex2[i]; }
  red[tid] = ls2; __syncthreads();
  for (int st = 128; st > 0; st >>= 1) { if (tid < st) red[tid] += red[tid + st]; __syncthreads(); }
  float inv2 = 1.f / red[0];
  for (int i = 0; i < 4; ++i) gtgt[(size_t)h * 1024 + tid + 256 * i] = ex2[i] * inv2;
}

extern "C" void kernel_launch(void* const* d_in, const int* in_sizes, int n_in,
                              void* d_out, int out_size, void* d_ws, size_t ws_size,
                              hipStream_t stream) {
  const float* hidden = (const float*)d_in[0];
  const float* cosp   = (const float*)d_in[1];
  const float* sinp   = (const float*)d_in[2];
  const float* Wq     = (const float*)d_in[3];
  const float* Wk     = (const float*)d_in[4];
  const float* Wv     = (const float*)d_in[5];
  const float* Wo     = (const float*)d_in[6];
  const float* Wgq    = (const float*)d_in[7];
  const float* Wgk    = (const float*)d_in[8];

  char* ws = (char*)d_ws;
  // ws layout (total exactly 128 MiB):
  u16* wqb = (u16*)ws;                         // 33,554,432 B (Wq bf16; later Wo bf16)
  u16* wkb = (u16*)(ws + 33554432);            // 33,554,432 B (Wk bf16; later bmx/qmn/kmn)
  u16* hid = (u16*)(ws + 67108864);            // 16,777,216 B (hidden bf16; later ctx)
  u16* qbf = (u16*)(ws + 83886080);            // 16,777,216 B
  u16* kbf = (u16*)(ws + 100663296);           // 16,777,216 B
  u16* vtb = (u16*)(ws + 117440512);           // 16,777,216 B  -> end 134,217,728
  // aliases (regions free after qkv_gemm):
  float* bmx = (float*)(ws + 33554432);        // 131,072 B
  float* qmn = (float*)(ws + 33554432 + 131072);
  float* kmn = (float*)(ws + 33554432 + 655360);
  u16* ctx = hid;                              // hid dead after qkv_gemm
  u16* wvb = (u16*)d_out;                      // Wv bf16 staged in d_out scratch (33.5 MB);
                                               // overwritten by gemm_out at the end.

  float* attn_out = (float*)d_out;
  float* gpred = attn_out + (size_t)S_LEN * EMB;
  float* gtgt  = gpred + NHEAD * NBLK * NBLK;

  conv3_f32_bf16<<<dim3(16384, 3), 256, 0, stream>>>(Wq, Wk, Wv, wqb, wkb, wvb, 4194304);
  conv_f32_bf16<<<8192, 256, 0, stream>>>(hidden, hid, 2097152);

  static bool attr_set = false;
  if (!attr_set) {
    (void)hipFuncSetAttribute((const void*)qkv_gemm_256,
                              hipFuncAttributeMaxDynamicSharedMemorySize, 131072);
    attr_set = true;
  }
  qkv_gemm_256<<<dim3(48, 8), 512, 131072, stream>>>(hid, wqb, wkb, wvb, qbf, kbf, vtb, cosp, sinp);

  conv_f32_bf16<<<16384, 256, 0, stream>>>(Wo, wqb, 4194304);  // wqb free after qkv_gemm

  attn_fwd<<<dim3(16, NHEAD), 256, 0, stream>>>(qbf, kbf, vtb, ctx, bmx);

  bmean2<<<dim3(NBLK, NHEAD, 2), 128, 0, stream>>>(qbf, kbf, qmn, kmn);
  gate_kernel<<<NHEAD, 256, 0, stream>>>(qmn, kmn, Wgq, Wgk, bmx, gpred, gtgt);

  gemm_out<<<dim3(32, 16), 256, 0, stream>>>(ctx, wqb, attn_out);
}

// Round 5
// 753.224 us; speedup vs baseline: 1.2548x; 1.0126x over previous
//
#include <hip/hip_runtime.h>
#include <stdint.h>

#define S_LEN 2048
#define EMB   4096
#define NHEAD 32
#define DHEAD 128
#define NBLK  32
#define GDIM  64

typedef float  f32x4  __attribute__((ext_vector_type(4)));
typedef __bf16 bf16x8 __attribute__((ext_vector_type(8)));
typedef unsigned short u16;

__device__ __forceinline__ u16 f2bf(float f) {
  uint32_t u = __float_as_uint(f);
  u += 0x7fffu + ((u >> 16) & 1u);
  return (u16)(u >> 16);
}
__device__ __forceinline__ float bf2f(u16 u) {
  return __uint_as_float(((uint32_t)u) << 16);
}

__device__ __forceinline__ void ld_lds16(const u16* g, u16* l) {
  __builtin_amdgcn_global_load_lds((const __attribute__((address_space(1))) void*)g,
                                   (__attribute__((address_space(3))) void*)l, 16, 0, 0);
}

// fp32 -> bf16 bulk convert (vectorized, n4 = n/4)
__global__ void conv_f32_bf16(const float* __restrict__ in, u16* __restrict__ out, int n4) {
  int i = blockIdx.x * 256 + threadIdx.x;
  if (i >= n4) return;
  float4 v = ((const float4*)in)[i];
  ushort4 o;
  o.x = f2bf(v.x); o.y = f2bf(v.y); o.z = f2bf(v.z); o.w = f2bf(v.w);
  ((ushort4*)out)[i] = o;
}

// three weights in one dispatch (grid.y selects)
__global__ void conv3_f32_bf16(const float* __restrict__ a, const float* __restrict__ b,
                               const float* __restrict__ c, u16* __restrict__ oa,
                               u16* __restrict__ ob, u16* __restrict__ oc, int n4) {
  int i = blockIdx.x * 256 + threadIdx.x;
  if (i >= n4) return;
  const float* in = (blockIdx.y == 0) ? a : (blockIdx.y == 1) ? b : c;
  u16* out = (blockIdx.y == 0) ? oa : (blockIdx.y == 1) ? ob : oc;
  float4 v = ((const float4*)in)[i];
  ushort4 o;
  o.x = f2bf(v.x); o.y = f2bf(v.y); o.z = f2bf(v.z); o.w = f2bf(v.w);
  ((ushort4*)out)[i] = o;
}

// ---------------------------------------------------------------------------
// Fused QKV projection, 256x128 tile / BK=64 / double-buffered 1-barrier loop.
// grid (96, 8) = 768 blocks -> EXACTLY 3 full rounds of 256 CUs (no tail; the
// r1/r4 256x256 grid of 384 ran 1.5 rounds = 75% utilization).
// blockIdx.x = which*32 + nt (nt = head, BN=128=DHEAD), blockIdx.y = m-tile.
// 512 thr = 8 waves (4M x 2N), per-wave 64x64 out (acc[4][4]).
// LDS 96 KiB: A[2 dbuf][256x64 bf16], B[2 dbuf][128x64 bf16] -> 1 block/CU.
// Per K-tile: issue 6 global_load_lds (t+1) -> 16 swizzled ds_reads -> 32 MFMA
// (compiler fine-grained lgkm interleave; setprio) -> vmcnt(0) (drain covered
// by a full tile of compute since issue) -> s_barrier.
// Swizzle: phys slot = logical ^ (row&7) (16B slots, 128B rows); applied on
// the pre-swizzled GLOBAL source (linear global_load_lds dest) and on ds_read.
// N-frag cols {c, c+16, c+64, c+80}, c = wn*32 -> RoPE pairs (ni, ni+2) are
// wave-local.
// ---------------------------------------------------------------------------
__global__ void __launch_bounds__(512, 2) qkv_gemm_256(
    const u16* __restrict__ A, const u16* __restrict__ Bq, const u16* __restrict__ Bk,
    const u16* __restrict__ Bv, u16* __restrict__ outq, u16* __restrict__ outk,
    u16* __restrict__ outvt, const float* __restrict__ cosp, const float* __restrict__ sinp)
{
  extern __shared__ u16 lds[];   // 49152 u16 = 96 KiB; A: [0,32768) B: [32768,49152)

  const int tid  = threadIdx.x;
  const int w    = tid >> 6;
  const int lane = tid & 63;
  const int r    = lane & 15;
  const int qd   = lane >> 4;
  const int wr   = w >> 1;            // M strip 0..3 (64 rows each)
  const int wn   = w & 1;             // N strip 0..1

  const int which = blockIdx.x >> 5;  // 0=Q 1=K 2=V
  const int nt    = blockIdx.x & 31;  // head
  const int m0    = blockIdx.y * 256;
  const int n0    = nt * 128;
  const int K     = EMB;
  const u16* Bm = (which == 0) ? Bq : (which == 1) ? Bk : Bv;

  // ds_read constants
  const int swz0 = (qd ^ (r & 7)) * 8;
  const int swz1 = ((4 + qd) ^ (r & 7)) * 8;
  const int rowbaseA = (wr * 64 + r) * 64;
  const int rowbaseB = (wn * 32 + r) * 64;

  // staging: thread covers LDS rows (tid>>3)+j*64, phys slot tid&7 holding
  // logical k-chunk (tid&7)^((tid>>3)&7) (pre-swizzled global source).
  const int srw = tid >> 3;
  const int sgs = ((tid & 7) ^ (srw & 7)) * 8;
  const u16* pA0 = A + (size_t)(m0 + srw) * K + sgs;
  const u16* pB0 = Bm + (size_t)(n0 + srw) * K + sgs;

  f32x4 acc[4][4];
#pragma unroll
  for (int mi = 0; mi < 4; ++mi)
#pragma unroll
    for (int ni = 0; ni < 4; ++ni) acc[mi][ni] = (f32x4){0.f, 0.f, 0.f, 0.f};

  auto stA = [&](int tt) {           // 4 loads: rows (tid>>3)+{0,64,128,192}
    u16* d = lds + (tt & 1) * 16384 + w * 512;
    const u16* g = pA0 + tt * 64;
    ld_lds16(g, d);
    ld_lds16(g + (size_t)64 * K, d + 4096);
    ld_lds16(g + (size_t)128 * K, d + 8192);
    ld_lds16(g + (size_t)192 * K, d + 12288);
  };
  auto stB = [&](int tt) {           // 2 loads: rows (tid>>3)+{0,64}
    u16* d = lds + 32768 + (tt & 1) * 8192 + w * 512;
    const u16* g = pB0 + tt * 64;
    ld_lds16(g, d);
    ld_lds16(g + (size_t)64 * K, d + 4096);
  };

  stA(0); stB(0);
  asm volatile("s_waitcnt vmcnt(0)" ::: "memory");
  __builtin_amdgcn_s_barrier();

  for (int t = 0; t < 64; ++t) {
    const u16* bufA = lds + (t & 1) * 16384;
    const u16* bufB = lds + 32768 + (t & 1) * 8192;
    if (t < 63) { stA(t + 1); stB(t + 1); }     // 6 loads into buf[t^1]

    bf16x8 aF[4][2], bF[4][2];
    {
      const u16* ab = bufA + rowbaseA;
#pragma unroll
      for (int mi = 0; mi < 4; ++mi) {
        aF[mi][0] = *(const bf16x8*)(ab + mi * 1024 + swz0);
        aF[mi][1] = *(const bf16x8*)(ab + mi * 1024 + swz1);
      }
      const u16* bb = bufB + rowbaseB;
      // n-frag row offsets within B: cols {0,16,64,80} (+wn*32 via rowbase)
      bF[0][0] = *(const bf16x8*)(bb + swz0);
      bF[0][1] = *(const bf16x8*)(bb + swz1);
      bF[1][0] = *(const bf16x8*)(bb + 1024 + swz0);
      bF[1][1] = *(const bf16x8*)(bb + 1024 + swz1);
      bF[2][0] = *(const bf16x8*)(bb + 4096 + swz0);
      bF[2][1] = *(const bf16x8*)(bb + 4096 + swz1);
      bF[3][0] = *(const bf16x8*)(bb + 5120 + swz0);
      bF[3][1] = *(const bf16x8*)(bb + 5120 + swz1);
    }

    __builtin_amdgcn_s_setprio(1);
#pragma unroll
    for (int mi = 0; mi < 4; ++mi)
#pragma unroll
      for (int ni = 0; ni < 4; ++ni) {
        acc[mi][ni] = __builtin_amdgcn_mfma_f32_16x16x32_bf16(aF[mi][0], bF[ni][0], acc[mi][ni], 0, 0, 0);
        acc[mi][ni] = __builtin_amdgcn_mfma_f32_16x16x32_bf16(aF[mi][1], bF[ni][1], acc[mi][ni], 0, 0, 0);
      }
    __builtin_amdgcn_s_setprio(0);

    if (t < 63) {
      asm volatile("s_waitcnt vmcnt(0)" ::: "memory");   // own 6 stages retired
      __builtin_amdgcn_s_barrier();                      // all waves' stages visible
    }
  }

  // C-frag: row = m0 + wr*64 + mi*16 + qd*4 + rg
  //         col = wn*32 + (ni&1)*16 + (ni>>1)*64 + r   (head nt)
  if (which < 2) {
    u16* out = which ? outk : outq;
#pragma unroll
    for (int mi = 0; mi < 4; ++mi) {
      const int rbase = m0 + wr * 64 + mi * 16 + qd * 4;
#pragma unroll
      for (int pp = 0; pp < 2; ++pp) {           // RoPE pairs (ni=pp, ni=pp+2)
        const int dlo = wn * 32 + pp * 16 + r;
#pragma unroll
        for (int rg = 0; rg < 4; ++rg) {
          int srow = rbase + rg;
          float c = cosp[srow * DHEAD + dlo];
          float s = sinp[srow * DHEAD + dlo];
          float lo = acc[mi][pp][rg], hi = acc[mi][pp + 2][rg];
          size_t base = ((size_t)nt * S_LEN + srow) * DHEAD;
          out[base + dlo]      = f2bf(lo * c - hi * s);
          out[base + dlo + 64] = f2bf(hi * c + lo * s);
        }
      }
    }
  } else {
    // V: transpose 256x128 tile through LDS -> (H, D, S). lT[128 cols][264]
    u16* lT = lds;
    __syncthreads();
#pragma unroll
    for (int mi = 0; mi < 4; ++mi) {
      const int lrow = wr * 64 + mi * 16 + qd * 4;
#pragma unroll
      for (int ni = 0; ni < 4; ++ni) {
        const int col = wn * 32 + (ni & 1) * 16 + (ni >> 1) * 64 + r;
#pragma unroll
        for (int rg = 0; rg < 4; ++rg)
          lT[col * 264 + lrow + rg] = f2bf(acc[mi][ni][rg]);
      }
    }
    __syncthreads();
#pragma unroll
    for (int i8 = 0; i8 < 8; ++i8) {
      const int flat = tid + i8 * 512;
      const int d = flat >> 5, sb = flat & 31;
      uint4 v = *(const uint4*)&lT[d * 264 + sb * 8];
      *(uint4*)&outvt[((size_t)nt * DHEAD + d) * S_LEN + m0 + sb * 8] = v;
    }
  }
}

// Output projection: C(2048x4096) = ctx @ Wo^T, f32 out. Natural dispatch order.
__global__ void __launch_bounds__(256, 2) gemm_out(
    const u16* __restrict__ A, const u16* __restrict__ B, float* __restrict__ out)
{
  __shared__ u16 lA[128 * 32];
  __shared__ u16 lB[128 * 32];
  const int tid = threadIdx.x;
  const int w = tid >> 6, lane = tid & 63;
  const int r = lane & 15, qd = lane >> 4;
  const int m0 = blockIdx.y * 128, n0 = blockIdx.x * 128;
  const int K = EMB;

  f32x4 acc[2][8];
#pragma unroll
  for (int mi = 0; mi < 2; ++mi)
#pragma unroll
    for (int ni = 0; ni < 8; ++ni) acc[mi][ni] = (f32x4){0.f, 0.f, 0.f, 0.f};

  const u16* Ab = A + (size_t)(m0 + w * 16 + (lane >> 2)) * K + (lane & 3) * 8;
  const u16* Bb = B + (size_t)(n0 + w * 16 + (lane >> 2)) * K + (lane & 3) * 8;
  u16* lAb = &lA[(w * 16) * 32];
  u16* lBb = &lB[(w * 16) * 32];

  for (int k0 = 0; k0 < K; k0 += 32) {
    __syncthreads();
    ld_lds16(Ab + k0, lAb);
    ld_lds16(Ab + (size_t)64 * K + k0, lAb + 64 * 32);
    ld_lds16(Bb + k0, lBb);
    ld_lds16(Bb + (size_t)64 * K + k0, lBb + 64 * 32);
    __syncthreads();
    bf16x8 af0 = *(const bf16x8*)&lA[(w * 32 + r) * 32 + qd * 8];
    bf16x8 af1 = *(const bf16x8*)&lA[(w * 32 + 16 + r) * 32 + qd * 8];
#pragma unroll
    for (int ni = 0; ni < 8; ++ni) {
      bf16x8 bf = *(const bf16x8*)&lB[(ni * 16 + r) * 32 + qd * 8];
      acc[0][ni] = __builtin_amdgcn_mfma_f32_16x16x32_bf16(af0, bf, acc[0][ni], 0, 0, 0);
      acc[1][ni] = __builtin_amdgcn_mfma_f32_16x16x32_bf16(af1, bf, acc[1][ni], 0, 0, 0);
    }
  }
#pragma unroll
  for (int mi = 0; mi < 2; ++mi)
#pragma unroll
    for (int ni = 0; ni < 8; ++ni)
#pragma unroll
      for (int rg = 0; rg < 4; ++rg) {
        int srow = m0 + w * 32 + mi * 16 + qd * 4 + rg;
        out[(size_t)srow * EMB + n0 + ni * 16 + r] = acc[mi][ni][rg];
      }
}

// ---------------------------------------------------------------------------
// flash attention with double-buffered global_load_lds staging + counted vmcnt.
// (unchanged from round 4 — verified passing)
// ---------------------------------------------------------------------------
__global__ void __launch_bounds__(256, 2) attn_fwd(
    const u16* __restrict__ qg, const u16* __restrict__ kg, const u16* __restrict__ vtg,
    u16* __restrict__ ctx, float* __restrict__ bmax)
{
  __shared__ u16 lK[2][64 * 128];
  __shared__ u16 lV[2][128 * 64];
  __shared__ u16 lP[64 * 76];
  __shared__ float lBM[4 * NBLK];

  const int tid = threadIdx.x;
  const int w = tid >> 6, lane = tid & 63;
  const int r = lane & 15, qd = lane >> 4;
  const int h = blockIdx.y;
  const u16* ksrc = kg + (size_t)h * S_LEN * DHEAD;
  const u16* vsrc = vtg + (size_t)h * DHEAD * S_LEN;
  const float scale = 0.08838834764831845f;

  // staging constants (per thread)
  const int ksl   = (lane & 15) ^ (w * 4 + (lane >> 4));       // K logical slot
  const int krow0 = w * 4 + (lane >> 4);                       // + i*16
  const u16* kg0  = ksrc + (size_t)krow0 * DHEAD + ksl * 8;
  const int vsl   = (lane & 7) ^ (lane >> 3);                  // V logical slot
  const int vrow0 = w * 8 + (lane >> 3);                       // + i*32
  const u16* vg0  = vsrc + (size_t)vrow0 * S_LEN + vsl * 8;

  for (int qsel = 0; qsel < 2; ++qsel) {
    const int qb = qsel ? (31 - (int)blockIdx.x) : (int)blockIdx.x;

    auto stage = [&](int kb, int buf) {
      u16* kd = &lK[buf][w * 512];
      const u16* kgp = kg0 + (size_t)kb * 64 * DHEAD;
#pragma unroll
      for (int i = 0; i < 4; ++i) ld_lds16(kgp + i * 16 * DHEAD, kd + i * 2048);
      u16* vd = &lV[buf][w * 512];
      const u16* vgp = vg0 + kb * 64;
#pragma unroll
      for (int i = 0; i < 4; ++i) ld_lds16(vgp + (size_t)i * 32 * S_LEN, vd + i * 2048);
    };

    stage(0, 0);                       // 8 loads/wave
    bf16x8 qf[4];
    {
      const u16* qp = qg + ((size_t)h * S_LEN + qb * 64 + w * 16 + r) * DHEAD + qd * 8;
#pragma unroll
      for (int ki = 0; ki < 4; ++ki) qf[ki] = *(const bf16x8*)(qp + ki * 32);
    }
    if (qb > 0) stage(1, 1);           // 8 more

    f32x4 o[8];
#pragma unroll
    for (int dt = 0; dt < 8; ++dt) o[dt] = (f32x4){0.f, 0.f, 0.f, 0.f};
    float m_run[4], l_run[4];
#pragma unroll
    for (int rg = 0; rg < 4; ++rg) { m_run[rg] = -__builtin_inff(); l_run[rg] = 0.f; }

    for (int kb = 0; kb <= qb; ++kb) {
      const int buf = kb & 1;
      // tile kb resident; tile kb+1 (8 loads) stays in flight.
      if (kb < qb) asm volatile("s_waitcnt vmcnt(8)" ::: "memory");
      else         asm volatile("s_waitcnt vmcnt(0)" ::: "memory");
      __builtin_amdgcn_s_barrier();

      f32x4 sf[4];
#pragma unroll
      for (int nt = 0; nt < 4; ++nt) sf[nt] = (f32x4){0.f, 0.f, 0.f, 0.f};
      __builtin_amdgcn_s_setprio(1);
#pragma unroll
      for (int ki = 0; ki < 4; ++ki)
#pragma unroll
        for (int nt = 0; nt < 4; ++nt) {
          bf16x8 bf = *(const bf16x8*)&lK[buf][(nt * 16 + r) * 128 + (((ki << 2) + qd) ^ r) * 8];
          sf[nt] = __builtin_amdgcn_mfma_f32_16x16x32_bf16(qf[ki], bf, sf[nt], 0, 0, 0);
        }
      __builtin_amdgcn_s_setprio(0);

      float rmax[4];
#pragma unroll
      for (int rg = 0; rg < 4; ++rg) rmax[rg] = -__builtin_inff();
#pragma unroll
      for (int nt = 0; nt < 4; ++nt)
#pragma unroll
        for (int rg = 0; rg < 4; ++rg) {
          float s = sf[nt][rg] * scale;
          if (kb == qb) {
            int col = nt * 16 + r, row = w * 16 + qd * 4 + rg;
            if (col > row) s = -__builtin_inff();
          }
          sf[nt][rg] = s;
          rmax[rg] = fmaxf(rmax[rg], s);
        }
#pragma unroll
      for (int rg = 0; rg < 4; ++rg) {
        float v = rmax[rg];
        v = fmaxf(v, __shfl_xor(v, 1));
        v = fmaxf(v, __shfl_xor(v, 2));
        v = fmaxf(v, __shfl_xor(v, 4));
        v = fmaxf(v, __shfl_xor(v, 8));
        rmax[rg] = v;
      }
      {  // per-wave tile max -> lBM for gate_target block_max
        float v = fmaxf(fmaxf(rmax[0], rmax[1]), fmaxf(rmax[2], rmax[3]));
        v = fmaxf(v, __shfl_xor(v, 16));
        v = fmaxf(v, __shfl_xor(v, 32));
        if (lane == 0) lBM[w * NBLK + kb] = v;
      }

      float alpha[4], rsum[4];
#pragma unroll
      for (int rg = 0; rg < 4; ++rg) {
        float mn = fmaxf(m_run[rg], rmax[rg]);
        alpha[rg] = __expf(m_run[rg] - mn);
        m_run[rg] = mn;
        rsum[rg] = 0.f;
      }
#pragma unroll
      for (int nt = 0; nt < 4; ++nt)
#pragma unroll
        for (int rg = 0; rg < 4; ++rg) {
          float p = __expf(sf[nt][rg] - m_run[rg]);
          sf[nt][rg] = p;
          rsum[rg] += p;
        }
#pragma unroll
      for (int rg = 0; rg < 4; ++rg) {
        float v = rsum[rg];
        v += __shfl_xor(v, 1);
        v += __shfl_xor(v, 2);
        v += __shfl_xor(v, 4);
        v += __shfl_xor(v, 8);
        l_run[rg] = l_run[rg] * alpha[rg] + v;
      }
      // P (C-layout) -> LDS -> A-layout; wave-private rows
#pragma unroll
      for (int nt = 0; nt < 4; ++nt)
#pragma unroll
        for (int rg = 0; rg < 4; ++rg)
          lP[(w * 16 + qd * 4 + rg) * 76 + nt * 16 + r] = f2bf(sf[nt][rg]);
#pragma unroll
      for (int dt = 0; dt < 8; ++dt)
#pragma unroll
        for (int rg = 0; rg < 4; ++rg) o[dt][rg] *= alpha[rg];
      bf16x8 pa0 = *(const bf16x8*)&lP[(w * 16 + r) * 76 + qd * 8];
      bf16x8 pa1 = *(const bf16x8*)&lP[(w * 16 + r) * 76 + 32 + qd * 8];
      __builtin_amdgcn_s_setprio(1);
#pragma unroll
      for (int dt = 0; dt < 8; ++dt) {
        bf16x8 bv0 = *(const bf16x8*)&lV[buf][(dt * 16 + r) * 64 + (qd ^ (r & 7)) * 8];
        bf16x8 bv1 = *(const bf16x8*)&lV[buf][(dt * 16 + r) * 64 + (((4 + qd)) ^ (r & 7)) * 8];
        o[dt] = __builtin_amdgcn_mfma_f32_16x16x32_bf16(pa0, bv0, o[dt], 0, 0, 0);
        o[dt] = __builtin_amdgcn_mfma_f32_16x16x32_bf16(pa1, bv1, o[dt], 0, 0, 0);
      }
      __builtin_amdgcn_s_setprio(0);

      __builtin_amdgcn_s_barrier();    // all waves done reading buf before restage
      if (kb + 2 <= qb) stage(kb + 2, buf);
    }

    float inv[4];
#pragma unroll
    for (int rg = 0; rg < 4; ++rg) inv[rg] = 1.f / l_run[rg];
#pragma unroll
    for (int dt = 0; dt < 8; ++dt)
#pragma unroll
      for (int rg = 0; rg < 4; ++rg) {
        int srow = qb * 64 + w * 16 + qd * 4 + rg;
        ctx[(size_t)srow * EMB + h * DHEAD + dt * 16 + r] = f2bf(o[dt][rg] * inv[rg]);
      }
    __syncthreads();
    if (tid <= qb) {
      float v = fmaxf(fmaxf(lBM[0 * NBLK + tid], lBM[1 * NBLK + tid]),
                      fmaxf(lBM[2 * NBLK + tid], lBM[3 * NBLK + tid]));
      bmax[((size_t)h * NBLK + qb) * NBLK + tid] = v;
    }
    __syncthreads();   // lBM reused next qsel
  }
}

// per-(h,nb) mean over 64 rows, q and k in one dispatch (grid.z selects). 128 thr, u32 loads.
__global__ void bmean2(const u16* __restrict__ q, const u16* __restrict__ k,
                       float* __restrict__ qo, float* __restrict__ ko) {
  int nb = blockIdx.x, h = blockIdx.y, t = threadIdx.x;
  const u16* x = blockIdx.z ? k : q;
  float* out = blockIdx.z ? ko : qo;
  const u16* p = x + ((size_t)h * S_LEN + nb * 64) * DHEAD + t * 2;
  float s0 = 0.f, s1 = 0.f;
#pragma unroll 8
  for (int i = 0; i < 64; ++i) {
    uint32_t v = *(const uint32_t*)(p + (size_t)i * DHEAD);
    s0 += bf2f((u16)v);
    s1 += bf2f((u16)(v >> 16));
  }
  float2 rr = {s0 * (1.f / 64.f), s1 * (1.f / 64.f)};
  *(float2*)&out[((size_t)h * NBLK + nb) * DHEAD + t * 2] = rr;
}

// gate_pred + gate_target, one block per head
__global__ void __launch_bounds__(256) gate_kernel(
    const float* __restrict__ qm, const float* __restrict__ km,
    const float* __restrict__ Wgq, const float* __restrict__ Wgk,
    const float* __restrict__ bmx, float* __restrict__ gpred, float* __restrict__ gtgt)
{
  __shared__ float gq[NBLK * GDIM], gk[NBLK * GDIM];
  __shared__ float red[256];
  const int h = blockIdx.x, tid = threadIdx.x;

  for (int i = 0; i < 8; ++i) {
    int e = tid + 256 * i;
    int n = e >> 6, g = e & 63;
    const float* qrow = qm + ((size_t)h * NBLK + n) * DHEAD;
    const float* krow = km + ((size_t)h * NBLK + n) * DHEAD;
    const float* wq = Wgq + g * DHEAD;
    const float* wk = Wgk + g * DHEAD;
    float s1 = 0.f, s2 = 0.f;
    for (int d = 0; d < DHEAD; ++d) { s1 += qrow[d] * wq[d]; s2 += krow[d] * wk[d]; }
    gq[e] = s1; gk[e] = s2;
  }
  __syncthreads();

  float gl[4];
  for (int i = 0; i < 4; ++i) {
    int idx = tid + 256 * i;
    int qn = idx >> 5, kn = idx & 31;
    if (kn <= qn) {
      float s = 0.f;
      for (int g = 0; g < GDIM; ++g) s += gq[qn * GDIM + g] * gk[kn * GDIM + g];
      gl[i] = s * 0.125f;
    } else gl[i] = -__builtin_inff();
  }
  float mx = fmaxf(fmaxf(gl[0], gl[1]), fmaxf(gl[2], gl[3]));
  red[tid] = mx; __syncthreads();
  for (int st = 128; st > 0; st >>= 1) { if (tid < st) red[tid] = fmaxf(red[tid], red[tid + st]); __syncthreads(); }
  float gmax = red[0]; __syncthreads();
  float ex[4], lsum = 0.f;
  for (int i = 0; i < 4; ++i) { ex[i] = __expf(gl[i] - gmax); lsum += ex[i]; }
  red[tid] = lsum; __syncthreads();
  for (int st = 128; st > 0; st >>= 1) { if (tid < st) red[tid] += red[tid + st]; __syncthreads(); }
  float invs = 1.f / red[0]; __syncthreads();
  for (int i = 0; i < 4; ++i) gpred[(size_t)h * 1024 + tid + 256 * i] = ex[i] * invs;

  float tl[4];
  for (int i = 0; i < 4; ++i) {
    int idx = tid + 256 * i;
    int qn = idx >> 5, kn = idx & 31;
    tl[i] = (kn <= qn) ? fminf(fmaxf(bmx[(size_t)h * 1024 + idx], -50.f), 50.f) * 0.5f
                       : -__builtin_inff();
  }
  float mx2 = fmaxf(fmaxf(tl[0], tl[1]), fmaxf(tl[2], tl[3]));
  red[tid] = mx2; __syncthreads();
  for (int st = 128; st > 0; st >>= 1) { if (tid < st) red[tid] = fmaxf(red[tid], red[tid + st]); __syncthreads(); }
  float tmax = red[0]; __syncthreads();
  float ex2[4], ls2 = 0.f;
  for (int i = 0; i < 4; ++i) { ex2[i] = __expf(tl[i] - tmax); ls2 += ex2[i]; }
  red[tid] = ls2; __syncthreads();
  for (int st = 128; st > 0; st >>= 1) { if (tid < st) red[tid] += red[tid + st]; __syncthreads(); }
  float inv2 = 1.f / red[0];
  for (int i = 0; i < 4; ++i) gtgt[(size_t)h * 1024 + tid + 256 * i] = ex2[i] * inv2;
}

extern "C" void kernel_launch(void* const* d_in, const int* in_sizes, int n_in,
                              void* d_out, int out_size, void* d_ws, size_t ws_size,
                              hipStream_t stream) {
  const float* hidden = (const float*)d_in[0];
  const float* cosp   = (const float*)d_in[1];
  const float* sinp   = (const float*)d_in[2];
  const float* Wq     = (const float*)d_in[3];
  const float* Wk     = (const float*)d_in[4];
  const float* Wv     = (const float*)d_in[5];
  const float* Wo     = (const float*)d_in[6];
  const float* Wgq    = (const float*)d_in[7];
  const float* Wgk    = (const float*)d_in[8];

  char* ws = (char*)d_ws;
  // ws layout (total exactly 128 MiB):
  u16* wqb = (u16*)ws;                         // 33,554,432 B (Wq bf16; later Wo bf16)
  u16* wkb = (u16*)(ws + 33554432);            // 33,554,432 B (Wk bf16; later bmx/qmn/kmn)
  u16* hid = (u16*)(ws + 67108864);            // 16,777,216 B (hidden bf16; later ctx)
  u16* qbf = (u16*)(ws + 83886080);            // 16,777,216 B
  u16* kbf = (u16*)(ws + 100663296);           // 16,777,216 B
  u16* vtb = (u16*)(ws + 117440512);           // 16,777,216 B  -> end 134,217,728
  // aliases (regions free after qkv_gemm):
  float* bmx = (float*)(ws + 33554432);        // 131,072 B
  float* qmn = (float*)(ws + 33554432 + 131072);
  float* kmn = (float*)(ws + 33554432 + 655360);
  u16* ctx = hid;                              // hid dead after qkv_gemm
  u16* wvb = (u16*)d_out;                      // Wv bf16 staged in d_out scratch (33.5 MB);
                                               // overwritten by gemm_out at the end.

  float* attn_out = (float*)d_out;
  float* gpred = attn_out + (size_t)S_LEN * EMB;
  float* gtgt  = gpred + NHEAD * NBLK * NBLK;

  conv3_f32_bf16<<<dim3(16384, 3), 256, 0, stream>>>(Wq, Wk, Wv, wqb, wkb, wvb, 4194304);
  conv_f32_bf16<<<8192, 256, 0, stream>>>(hidden, hid, 2097152);

  static bool attr_set = false;
  if (!attr_set) {
    (void)hipFuncSetAttribute((const void*)qkv_gemm_256,
                              hipFuncAttributeMaxDynamicSharedMemorySize, 98304);
    attr_set = true;
  }
  qkv_gemm_256<<<dim3(96, 8), 512, 98304, stream>>>(hid, wqb, wkb, wvb, qbf, kbf, vtb, cosp, sinp);

  conv_f32_bf16<<<16384, 256, 0, stream>>>(Wo, wqb, 4194304);  // wqb free after qkv_gemm

  attn_fwd<<<dim3(16, NHEAD), 256, 0, stream>>>(qbf, kbf, vtb, ctx, bmx);

  bmean2<<<dim3(NBLK, NHEAD, 2), 128, 0, stream>>>(qbf, kbf, qmn, kmn);
  gate_kernel<<<NHEAD, 256, 0, stream>>>(qmn, kmn, Wgq, Wgk, bmx, gpred, gtgt);

  gemm_out<<<dim3(32, 16), 256, 0, stream>>>(ctx, wqb, attn_out);
}